// Round 5
// baseline (603.119 us; speedup 1.0000x reference)
//
#include <hip/hip_runtime.h>
#include <math.h>

#define NN 100000      // nodes
#define CD 32          // classes / hidden
#define NPB 4          // nodes per block in fused layer kernel (1 wave each)
#define PAD 16         // ints per counter slot (64B line) — kills false sharing

#define SCAN_EPB 512                                   // counts per scan block
#define SCAN_NB  ((NN + SCAN_EPB - 1) / SCAN_EPB)      // 196 blocks

// ---------------------------------------------------------------------------
// Detect whether edge_index is int64 or int32 on-device (JAX x64-off makes it
// int32 despite the reference saying int64). One wave checks 512 values.
__global__ void detect_idx64(const void* edge, int* flag) {
    const long long* p = (const long long*)edge;
    int lane = threadIdx.x & 63;
    int bad = 0;
    for (int i = lane; i < 512; i += 64) {
        long long v = p[i];
        if (v < 0 || v >= NN) bad = 1;
    }
    unsigned long long anybad = __ballot(bad);
    if (lane == 0) *flag = (anybad == 0ULL) ? 1 : 0;
}

__device__ __forceinline__ int load_idx(const void* edge, int i, int is64) {
    if (is64) return (int)((const long long*)edge)[i];
    return ((const int*)edge)[i];
}

// ---------------------------------------------------------------------------
// CSR build: histogram of dst, parallel exclusive scan, scatter src ids.
// counts/cursor are PADDED (one int per 64B line) and alias the h1 region.
__global__ void hist_kernel(const void* edge, int E, const int* flag,
                            int* __restrict__ counts) {
    const int is64 = *flag;
    const int stride = gridDim.x * blockDim.x;
    for (int e = blockIdx.x * blockDim.x + threadIdx.x; e < E; e += stride) {
        int dst = load_idx(edge, E + e, is64);
        atomicAdd(&counts[dst * PAD], 1);     // no return value -> fire & forget
    }
}

__global__ void scan_partial_kernel(const int* __restrict__ counts,
                                    int* __restrict__ blockSums) {
    __shared__ int red[256];
    const int b = blockIdx.x, t = threadIdx.x;
    const int base = b * SCAN_EPB + t * 2;
    int s = 0;
    if (base < NN)     s += counts[base * PAD];
    if (base + 1 < NN) s += counts[(base + 1) * PAD];
    red[t] = s;
    __syncthreads();
    for (int off = 128; off > 0; off >>= 1) {
        if (t < off) red[t] += red[t + off];
        __syncthreads();
    }
    if (t == 0) blockSums[b] = red[0];
}

__global__ void scan_bases_kernel(int* blockSums) {
    __shared__ int tmp[SCAN_NB];
    const int t = threadIdx.x;
    if (t < SCAN_NB) tmp[t] = blockSums[t];
    __syncthreads();
    if (t == 0) {
        int run = 0;
        for (int i = 0; i < SCAN_NB; ++i) { int c = tmp[i]; tmp[i] = run; run += c; }
    }
    __syncthreads();
    if (t < SCAN_NB) blockSums[t] = tmp[t];
}

// Reads padded counts, writes dense offsets + padded cursor (cursor aliases
// counts: each padded slot is read then written by the same thread — safe).
__global__ void scan_final_kernel(const int* __restrict__ counts,
                                  const int* __restrict__ blockSums,
                                  int* __restrict__ offsets,
                                  int* __restrict__ cursor) {
    __shared__ int tsum[256];
    const int b = blockIdx.x, t = threadIdx.x;
    const int base = b * SCAN_EPB + t * 2;
    const int c0 = (base < NN)     ? counts[base * PAD]       : 0;
    const int c1 = (base + 1 < NN) ? counts[(base + 1) * PAD] : 0;
    tsum[t] = c0 + c1;
    __syncthreads();
    for (int off = 1; off < 256; off <<= 1) {
        int u = (t >= off) ? tsum[t - off] : 0;
        __syncthreads();
        tsum[t] += u;
        __syncthreads();
    }
    const int bbase = blockSums[b];
    const int excl  = tsum[t] - (c0 + c1);
    if (base < NN) {
        int o = bbase + excl;
        offsets[base] = o; cursor[base * PAD] = o;
        if (base + 1 < NN) {
            int o1 = o + c0;
            offsets[base + 1] = o1; cursor[(base + 1) * PAD] = o1;
        }
    }
    if (b == SCAN_NB - 1 && t == 255) offsets[NN] = bbase + tsum[255];  // == E
}

__global__ void fill_kernel(const void* edge, int E, const int* flag,
                            int* cursor, int* __restrict__ csr_src) {
    const int is64 = *flag;
    const int stride = gridDim.x * blockDim.x;
    for (int e = blockIdx.x * blockDim.x + threadIdx.x; e < E; e += stride) {
        int s = load_idx(edge, e, is64);
        int d = load_idx(edge, E + e, is64);
        int pos = atomicAdd(&cursor[d * PAD], 1);
        csr_src[pos] = s;
    }
}

// ---------------------------------------------------------------------------
// Fused SAGE layer: gather-max over neighbors + dual dense (+ relu / log_sm).
// One 64-lane wave per node, NPB nodes per 256-thread block.
// Gather: unroll x4 for MLP; DIN==32 additionally packs 2 neighbors per wave.
// Dense: k-loop split across wave halves, combined with one 64-wide shfl.
// MODE: 0 = relu, 2 = log_softmax (final layer).
template <int DIN, int MODE>
__global__ void sage_layer_kernel(const float* __restrict__ h,
                                  const int* __restrict__ offsets,
                                  const int* __restrict__ csr_src,
                                  const float* __restrict__ Wl,
                                  const float* __restrict__ bl,
                                  const float* __restrict__ Wr,
                                  float* __restrict__ out) {
    __shared__ float sWl[DIN * CD];
    __shared__ float sWr[DIN * CD];
    __shared__ float sb[CD];
    __shared__ float sAgg[NPB][DIN];
    __shared__ float sH[NPB][DIN];

    const int tid = threadIdx.x;
    for (int i = tid; i < DIN * CD; i += blockDim.x) {
        sWl[i] = Wl[i];
        sWr[i] = Wr[i];
    }
    if (tid < CD) sb[tid] = bl[tid];

    const int g    = tid >> 6;        // wave id = local node
    const int lane = tid & 63;
    const int n    = blockIdx.x * NPB + g;

    if (n < NN) {
        const int beg = offsets[n];
        const int end = offsets[n + 1];
        if (DIN == 32) {
            // 2 neighbors per wave: lane = p*32 + j; unroll x2 per half.
            const int p = lane >> 5;
            const int j = lane & 31;
            float a0 = -INFINITY, a1 = -INFINITY;
            int i = beg + p;
            for (; i + 2 < end; i += 4) {
                int s0 = csr_src[i];
                int s1 = csr_src[i + 2];
                a0 = fmaxf(a0, h[(size_t)s0 * 32 + j]);
                a1 = fmaxf(a1, h[(size_t)s1 * 32 + j]);
            }
            for (; i < end; i += 2)
                a0 = fmaxf(a0, h[(size_t)csr_src[i] * 32 + j]);
            float a = fmaxf(a0, a1);
            a = fmaxf(a, __shfl_xor(a, 32));          // combine halves
            if (lane < 32) {
                sAgg[g][j] = (a == -INFINITY) ? 0.0f : a;
                sH[g][j]   = h[(size_t)n * 32 + j];
            }
        } else {
            if (lane < DIN) {
                float a0 = -INFINITY, a1 = -INFINITY, a2 = -INFINITY, a3 = -INFINITY;
                int i = beg;
                for (; i + 4 <= end; i += 4) {
                    int s0 = csr_src[i],     s1 = csr_src[i + 1];
                    int s2 = csr_src[i + 2], s3 = csr_src[i + 3];
                    a0 = fmaxf(a0, h[(size_t)s0 * DIN + lane]);
                    a1 = fmaxf(a1, h[(size_t)s1 * DIN + lane]);
                    a2 = fmaxf(a2, h[(size_t)s2 * DIN + lane]);
                    a3 = fmaxf(a3, h[(size_t)s3 * DIN + lane]);
                }
                for (; i < end; ++i)
                    a0 = fmaxf(a0, h[(size_t)csr_src[i] * DIN + lane]);
                float a = fmaxf(fmaxf(a0, a1), fmaxf(a2, a3));
                sAgg[g][lane] = (a == -INFINITY) ? 0.0f : a;
                sH[g][lane]   = h[(size_t)n * DIN + lane];
            }
        }
    }
    __syncthreads();

    if (n < NN) {
        // Dense: halves of the wave split the k-range, shfl-combine.
        const int p  = lane >> 5;
        const int j  = lane & 31;
        const int KH = DIN / 2;                  // 25 or 16
        const int k0 = p * KH;
        const int k1 = (p == 1) ? DIN : KH;      // second half takes remainder
        float part = (p == 0) ? sb[j] : 0.0f;
#pragma unroll
        for (int k = k0; k < k1; ++k) {
            part += sAgg[g][k] * sWl[k * CD + j] + sH[g][k] * sWr[k * CD + j];
        }
        float acc = part + __shfl_xor(part, 32);
        if (lane < 32) {
            if (MODE == 0) acc = fmaxf(acc, 0.0f);
            if (MODE == 2) {
                float m = acc;
                for (int off = 16; off > 0; off >>= 1) m = fmaxf(m, __shfl_xor(m, off, 32));
                float ex = expf(acc - m);
                float s = ex;
                for (int off = 16; off > 0; off >>= 1) s += __shfl_xor(s, off, 32);
                acc = acc - m - logf(s);
            }
            out[(size_t)n * CD + j] = acc;
        }
    }
}

// ---------------------------------------------------------------------------
extern "C" void kernel_launch(void* const* d_in, const int* in_sizes, int n_in,
                              void* d_out, int out_size, void* d_ws, size_t ws_size,
                              hipStream_t stream) {
    const float* x    = (const float*)d_in[0];
    const void*  edge = d_in[1];
    const float* Wl1 = (const float*)d_in[2];
    const float* bl1 = (const float*)d_in[3];
    const float* Wr1 = (const float*)d_in[4];
    const float* Wl2 = (const float*)d_in[5];
    const float* bl2 = (const float*)d_in[6];
    const float* Wr2 = (const float*)d_in[7];
    const float* Wl3 = (const float*)d_in[8];
    const float* bl3 = (const float*)d_in[9];
    const float* Wr3 = (const float*)d_in[10];

    const int E = in_sizes[1] / 2;

    // Workspace carve-up (256B aligned). Total ≈ 32.4 MB.
    // The padded counts/cursor array (6.4 MB) ALIASES h1: counters are dead
    // once fill_kernel completes; h1 is first written in layer 1 (after fill).
    char* ws = (char*)d_ws;
    size_t off = 0;
    auto carve = [&](size_t bytes) {
        void* p = ws + off;
        off = (off + bytes + 255) & ~(size_t)255;
        return p;
    };
    int*   offsets   = (int*)  carve((size_t)(NN + 1) * 4);
    int*   flag      = (int*)  carve(4);
    int*   blockSums = (int*)  carve((size_t)SCAN_NB * 4);
    int*   csr_src   = (int*)  carve((size_t)E * 4);
    float* h1        = (float*)carve((size_t)NN * CD * 4);
    float* h2        = (float*)carve((size_t)NN * CD * 4);
    int*   counts    = (int*)h1;          // padded: NN*PAD ints = 6.4 MB <= h1
    int*   cursor    = counts;
    float* out       = (float*)d_out;
    (void)ws_size; (void)n_in; (void)out_size;

    hipMemsetAsync(counts, 0, (size_t)NN * PAD * 4, stream);
    detect_idx64<<<1, 64, 0, stream>>>(edge, flag);

    const int eb4 = (E + 1023) / 1024;    // 4 edges per thread
    hist_kernel<<<eb4, 256, 0, stream>>>(edge, E, flag, counts);
    scan_partial_kernel<<<SCAN_NB, 256, 0, stream>>>(counts, blockSums);
    scan_bases_kernel<<<1, 256, 0, stream>>>(blockSums);
    scan_final_kernel<<<SCAN_NB, 256, 0, stream>>>(counts, blockSums, offsets, cursor);
    fill_kernel<<<eb4, 256, 0, stream>>>(edge, E, flag, cursor, csr_src);

    const int nb = (NN + NPB - 1) / NPB;   // 25000 blocks, 4 nodes each

    sage_layer_kernel<50, 0><<<nb, 256, 0, stream>>>(x,  offsets, csr_src, Wl1, bl1, Wr1, h1);
    sage_layer_kernel<32, 0><<<nb, 256, 0, stream>>>(h1, offsets, csr_src, Wl2, bl2, Wr2, h2);
    sage_layer_kernel<32, 2><<<nb, 256, 0, stream>>>(h2, offsets, csr_src, Wl3, bl3, Wr3, out);
}

// Round 6
// 541.985 us; speedup vs baseline: 1.1128x; 1.1128x over previous
//
#include <hip/hip_runtime.h>
#include <math.h>

#define NN 100000      // nodes
#define CD 32          // classes / hidden
#define NPB 4          // nodes per block in fused layer kernel (1 wave each)

#define SCAN_EPB 512                                   // counts per scan block
#define SCAN_NB  ((NN + SCAN_EPB - 1) / SCAN_EPB)      // 196 blocks

// ---------------------------------------------------------------------------
// Detect whether edge_index is int64 or int32 on-device (JAX x64-off makes it
// int32 despite the reference saying int64). One wave checks 512 values.
__global__ void detect_idx64(const void* edge, int* flag) {
    const long long* p = (const long long*)edge;
    int lane = threadIdx.x & 63;
    int bad = 0;
    for (int i = lane; i < 512; i += 64) {
        long long v = p[i];
        if (v < 0 || v >= NN) bad = 1;
    }
    unsigned long long anybad = __ballot(bad);
    if (lane == 0) *flag = (anybad == 0ULL) ? 1 : 0;
}

__device__ __forceinline__ int load_idx(const void* edge, int i, int is64) {
    if (is64) return (int)((const long long*)edge)[i];
    return ((const int*)edge)[i];
}

// ---------------------------------------------------------------------------
// CSR build: histogram of dst, parallel exclusive scan, scatter src ids.
// Counters PACKED (padding regressed in R5 — atomics resolve at L2/memory
// side; padding only bloats the working set). cursor aliases counts.
__global__ void hist_kernel(const void* edge, int E, const int* flag,
                            int* __restrict__ counts) {
    const int is64 = *flag;
    int e = blockIdx.x * blockDim.x + threadIdx.x;
    if (e >= E) return;
    int dst = load_idx(edge, E + e, is64);
    atomicAdd(&counts[dst], 1);            // no return value -> fire & forget
}

__global__ void scan_partial_kernel(const int* __restrict__ counts,
                                    int* __restrict__ blockSums) {
    __shared__ int red[256];
    const int b = blockIdx.x, t = threadIdx.x;
    const int base = b * SCAN_EPB + t * 2;
    int s = 0;
    if (base < NN)     s += counts[base];
    if (base + 1 < NN) s += counts[base + 1];
    red[t] = s;
    __syncthreads();
    for (int off = 128; off > 0; off >>= 1) {
        if (t < off) red[t] += red[t + off];
        __syncthreads();
    }
    if (t == 0) blockSums[b] = red[0];
}

__global__ void scan_bases_kernel(int* blockSums) {
    __shared__ int tmp[SCAN_NB];
    const int t = threadIdx.x;
    if (t < SCAN_NB) tmp[t] = blockSums[t];
    __syncthreads();
    if (t == 0) {
        int run = 0;
        for (int i = 0; i < SCAN_NB; ++i) { int c = tmp[i]; tmp[i] = run; run += c; }
    }
    __syncthreads();
    if (t < SCAN_NB) blockSums[t] = tmp[t];
}

// cursor aliases counts: each address is read then written by the same thread.
__global__ void scan_final_kernel(const int* __restrict__ counts,
                                  const int* __restrict__ blockSums,
                                  int* __restrict__ offsets,
                                  int* __restrict__ cursor) {
    __shared__ int tsum[256];
    const int b = blockIdx.x, t = threadIdx.x;
    const int base = b * SCAN_EPB + t * 2;
    const int c0 = (base < NN)     ? counts[base]     : 0;
    const int c1 = (base + 1 < NN) ? counts[base + 1] : 0;
    tsum[t] = c0 + c1;
    __syncthreads();
    for (int off = 1; off < 256; off <<= 1) {
        int u = (t >= off) ? tsum[t - off] : 0;
        __syncthreads();
        tsum[t] += u;
        __syncthreads();
    }
    const int bbase = blockSums[b];
    const int excl  = tsum[t] - (c0 + c1);
    if (base < NN) {
        int o = bbase + excl;
        offsets[base] = o; cursor[base] = o;
        if (base + 1 < NN) {
            int o1 = o + c0;
            offsets[base + 1] = o1; cursor[base + 1] = o1;
        }
    }
    if (b == SCAN_NB - 1 && t == 255) offsets[NN] = bbase + tsum[255];  // == E
}

// 4 edges per thread, straight-line: 4 coalesced index loads, 4 INDEPENDENT
// atomicAdds in flight (the R5 loop form serialized them), then 4 stores.
__global__ void fill_kernel(const void* edge, int E, const int* flag,
                            int* cursor, int* __restrict__ csr_src) {
    const int is64 = *flag;
    const int st   = blockDim.x;                       // 256
    const int e0   = blockIdx.x * (st * 4) + threadIdx.x;
    const int e1 = e0 + st, e2 = e0 + 2 * st, e3 = e0 + 3 * st;
    const bool v0 = e0 < E, v1 = e1 < E, v2 = e2 < E, v3 = e3 < E;

    int s0 = 0, d0 = 0, s1 = 0, d1 = 0, s2 = 0, d2 = 0, s3 = 0, d3 = 0;
    if (v0) { s0 = load_idx(edge, e0, is64); d0 = load_idx(edge, E + e0, is64); }
    if (v1) { s1 = load_idx(edge, e1, is64); d1 = load_idx(edge, E + e1, is64); }
    if (v2) { s2 = load_idx(edge, e2, is64); d2 = load_idx(edge, E + e2, is64); }
    if (v3) { s3 = load_idx(edge, e3, is64); d3 = load_idx(edge, E + e3, is64); }

    int p0 = 0, p1 = 0, p2 = 0, p3 = 0;
    if (v0) p0 = atomicAdd(&cursor[d0], 1);
    if (v1) p1 = atomicAdd(&cursor[d1], 1);
    if (v2) p2 = atomicAdd(&cursor[d2], 1);
    if (v3) p3 = atomicAdd(&cursor[d3], 1);

    if (v0) csr_src[p0] = s0;
    if (v1) csr_src[p1] = s1;
    if (v2) csr_src[p2] = s2;
    if (v3) csr_src[p3] = s3;
}

// ---------------------------------------------------------------------------
// Fused SAGE layer: gather-max over neighbors + dual dense (+ relu / log_sm).
// One 64-lane wave per node, NPB nodes per 256-thread block.
// MODE: 0 = relu, 2 = log_softmax (final layer).
template <int DIN, int MODE>
__global__ void sage_layer_kernel(const float* __restrict__ h,
                                  const int* __restrict__ offsets,
                                  const int* __restrict__ csr_src,
                                  const float* __restrict__ Wl,
                                  const float* __restrict__ bl,
                                  const float* __restrict__ Wr,
                                  float* __restrict__ out) {
    __shared__ float sWl[DIN * CD];
    __shared__ float sWr[DIN * CD];
    __shared__ float sb[CD];
    __shared__ float sAgg[NPB][DIN];
    __shared__ float sH[NPB][DIN];

    const int tid = threadIdx.x;
    for (int i = tid; i < DIN * CD; i += blockDim.x) {
        sWl[i] = Wl[i];
        sWr[i] = Wr[i];
    }
    if (tid < CD) sb[tid] = bl[tid];

    const int g    = tid >> 6;        // wave id = local node
    const int lane = tid & 63;
    const int n    = blockIdx.x * NPB + g;

    if (n < NN) {
        const int beg = offsets[n];
        const int end = offsets[n + 1];
        if (DIN == 32) {
            const int p = lane >> 5;
            const int j = lane & 31;
            float a0 = -INFINITY, a1 = -INFINITY;
            int i = beg + p;
            for (; i + 2 < end; i += 4) {
                int s0 = csr_src[i];
                int s1 = csr_src[i + 2];
                a0 = fmaxf(a0, h[(size_t)s0 * 32 + j]);
                a1 = fmaxf(a1, h[(size_t)s1 * 32 + j]);
            }
            for (; i < end; i += 2)
                a0 = fmaxf(a0, h[(size_t)csr_src[i] * 32 + j]);
            float a = fmaxf(a0, a1);
            a = fmaxf(a, __shfl_xor(a, 32));
            if (lane < 32) {
                sAgg[g][j] = (a == -INFINITY) ? 0.0f : a;
                sH[g][j]   = h[(size_t)n * 32 + j];
            }
        } else {
            if (lane < DIN) {
                float a0 = -INFINITY, a1 = -INFINITY, a2 = -INFINITY, a3 = -INFINITY;
                int i = beg;
                for (; i + 4 <= end; i += 4) {
                    int s0 = csr_src[i],     s1 = csr_src[i + 1];
                    int s2 = csr_src[i + 2], s3 = csr_src[i + 3];
                    a0 = fmaxf(a0, h[(size_t)s0 * DIN + lane]);
                    a1 = fmaxf(a1, h[(size_t)s1 * DIN + lane]);
                    a2 = fmaxf(a2, h[(size_t)s2 * DIN + lane]);
                    a3 = fmaxf(a3, h[(size_t)s3 * DIN + lane]);
                }
                for (; i < end; ++i)
                    a0 = fmaxf(a0, h[(size_t)csr_src[i] * DIN + lane]);
                float a = fmaxf(fmaxf(a0, a1), fmaxf(a2, a3));
                sAgg[g][lane] = (a == -INFINITY) ? 0.0f : a;
                sH[g][lane]   = h[(size_t)n * DIN + lane];
            }
        }
    }
    __syncthreads();

    if (n < NN) {
        const int p  = lane >> 5;
        const int j  = lane & 31;
        const int KH = DIN / 2;                  // 25 or 16
        const int k0 = p * KH;
        const int k1 = (p == 1) ? DIN : KH;
        float part = (p == 0) ? sb[j] : 0.0f;
#pragma unroll
        for (int k = k0; k < k1; ++k) {
            part += sAgg[g][k] * sWl[k * CD + j] + sH[g][k] * sWr[k * CD + j];
        }
        float acc = part + __shfl_xor(part, 32);
        if (lane < 32) {
            if (MODE == 0) acc = fmaxf(acc, 0.0f);
            if (MODE == 2) {
                float m = acc;
                for (int off = 16; off > 0; off >>= 1) m = fmaxf(m, __shfl_xor(m, off, 32));
                float ex = expf(acc - m);
                float s = ex;
                for (int off = 16; off > 0; off >>= 1) s += __shfl_xor(s, off, 32);
                acc = acc - m - logf(s);
            }
            out[(size_t)n * CD + j] = acc;
        }
    }
}

// ---------------------------------------------------------------------------
extern "C" void kernel_launch(void* const* d_in, const int* in_sizes, int n_in,
                              void* d_out, int out_size, void* d_ws, size_t ws_size,
                              hipStream_t stream) {
    const float* x    = (const float*)d_in[0];
    const void*  edge = d_in[1];
    const float* Wl1 = (const float*)d_in[2];
    const float* bl1 = (const float*)d_in[3];
    const float* Wr1 = (const float*)d_in[4];
    const float* Wl2 = (const float*)d_in[5];
    const float* bl2 = (const float*)d_in[6];
    const float* Wr2 = (const float*)d_in[7];
    const float* Wl3 = (const float*)d_in[8];
    const float* bl3 = (const float*)d_in[9];
    const float* Wr3 = (const float*)d_in[10];

    const int E = in_sizes[1] / 2;

    // Workspace carve-up (256B aligned). Total ≈ 32.8 MB.
    char* ws = (char*)d_ws;
    size_t off = 0;
    auto carve = [&](size_t bytes) {
        void* p = ws + off;
        off = (off + bytes + 255) & ~(size_t)255;
        return p;
    };
    int*   counts    = (int*)  carve((size_t)NN * 4);       // aliased as cursor
    int*   cursor    = counts;
    int*   offsets   = (int*)  carve((size_t)(NN + 1) * 4);
    int*   flag      = (int*)  carve(4);
    int*   blockSums = (int*)  carve((size_t)SCAN_NB * 4);
    int*   csr_src   = (int*)  carve((size_t)E * 4);
    float* h1        = (float*)carve((size_t)NN * CD * 4);
    float* h2        = (float*)carve((size_t)NN * CD * 4);
    float* out       = (float*)d_out;
    (void)ws_size; (void)n_in; (void)out_size;

    hipMemsetAsync(counts, 0, (size_t)NN * 4, stream);
    detect_idx64<<<1, 64, 0, stream>>>(edge, flag);

    const int eb1 = (E + 255) / 256;      // 1 edge/thread (hist: fire&forget)
    const int eb4 = (E + 1023) / 1024;    // 4 edges/thread (fill: batched ILP)
    hist_kernel<<<eb1, 256, 0, stream>>>(edge, E, flag, counts);
    scan_partial_kernel<<<SCAN_NB, 256, 0, stream>>>(counts, blockSums);
    scan_bases_kernel<<<1, 256, 0, stream>>>(blockSums);
    scan_final_kernel<<<SCAN_NB, 256, 0, stream>>>(counts, blockSums, offsets, cursor);
    fill_kernel<<<eb4, 256, 0, stream>>>(edge, E, flag, cursor, csr_src);

    const int nb = (NN + NPB - 1) / NPB;   // 25000 blocks, 4 nodes each

    sage_layer_kernel<50, 0><<<nb, 256, 0, stream>>>(x,  offsets, csr_src, Wl1, bl1, Wr1, h1);
    sage_layer_kernel<32, 0><<<nb, 256, 0, stream>>>(h1, offsets, csr_src, Wl2, bl2, Wr2, h2);
    sage_layer_kernel<32, 2><<<nb, 256, 0, stream>>>(h2, offsets, csr_src, Wl3, bl3, Wr3, out);
}

// Round 7
// 464.190 us; speedup vs baseline: 1.2993x; 1.1676x over previous
//
#include <hip/hip_runtime.h>
#include <math.h>

#define NN 100000      // nodes
#define CD 32          // classes / hidden
#define NPB 4          // nodes (waves) per block in fused layer kernel
#define LGRID 2048     // persistent layer blocks (8/CU resident)

#define SCAN_EPB 512                                   // counts per scan block
#define SCAN_NB  ((NN + SCAN_EPB - 1) / SCAN_EPB)      // 196 blocks

// ---------------------------------------------------------------------------
__global__ void detect_idx64(const void* edge, int* flag) {
    const long long* p = (const long long*)edge;
    int lane = threadIdx.x & 63;
    int bad = 0;
    for (int i = lane; i < 512; i += 64) {
        long long v = p[i];
        if (v < 0 || v >= NN) bad = 1;
    }
    unsigned long long anybad = __ballot(bad);
    if (lane == 0) *flag = (anybad == 0ULL) ? 1 : 0;
}

__device__ __forceinline__ int load_idx(const void* edge, int i, int is64) {
    if (is64) return (int)((const long long*)edge)[i];
    return ((const int*)edge)[i];
}

// ---------------------------------------------------------------------------
// CSR build (packed counters; cursor aliases counts).
__global__ void hist_kernel(const void* edge, int E, const int* flag,
                            int* __restrict__ counts) {
    const int is64 = *flag;
    int e = blockIdx.x * blockDim.x + threadIdx.x;
    if (e >= E) return;
    int dst = load_idx(edge, E + e, is64);
    atomicAdd(&counts[dst], 1);            // fire & forget
}

__global__ void scan_partial_kernel(const int* __restrict__ counts,
                                    int* __restrict__ blockSums) {
    __shared__ int red[256];
    const int b = blockIdx.x, t = threadIdx.x;
    const int base = b * SCAN_EPB + t * 2;
    int s = 0;
    if (base < NN)     s += counts[base];
    if (base + 1 < NN) s += counts[base + 1];
    red[t] = s;
    __syncthreads();
    for (int off = 128; off > 0; off >>= 1) {
        if (t < off) red[t] += red[t + off];
        __syncthreads();
    }
    if (t == 0) blockSums[b] = red[0];
}

__global__ void scan_bases_kernel(int* blockSums) {
    __shared__ int tmp[SCAN_NB];
    const int t = threadIdx.x;
    if (t < SCAN_NB) tmp[t] = blockSums[t];
    __syncthreads();
    if (t == 0) {
        int run = 0;
        for (int i = 0; i < SCAN_NB; ++i) { int c = tmp[i]; tmp[i] = run; run += c; }
    }
    __syncthreads();
    if (t < SCAN_NB) blockSums[t] = tmp[t];
}

__global__ void scan_final_kernel(const int* __restrict__ counts,
                                  const int* __restrict__ blockSums,
                                  int* __restrict__ offsets,
                                  int* __restrict__ cursor) {
    __shared__ int tsum[256];
    const int b = blockIdx.x, t = threadIdx.x;
    const int base = b * SCAN_EPB + t * 2;
    const int c0 = (base < NN)     ? counts[base]     : 0;
    const int c1 = (base + 1 < NN) ? counts[base + 1] : 0;
    tsum[t] = c0 + c1;
    __syncthreads();
    for (int off = 1; off < 256; off <<= 1) {
        int u = (t >= off) ? tsum[t - off] : 0;
        __syncthreads();
        tsum[t] += u;
        __syncthreads();
    }
    const int bbase = blockSums[b];
    const int excl  = tsum[t] - (c0 + c1);
    if (base < NN) {
        int o = bbase + excl;
        offsets[base] = o; cursor[base] = o;
        if (base + 1 < NN) {
            int o1 = o + c0;
            offsets[base + 1] = o1; cursor[base + 1] = o1;
        }
    }
    if (b == SCAN_NB - 1 && t == 255) offsets[NN] = bbase + tsum[255];  // == E
}

// 4 edges/thread straight-line: 4 independent atomicAdds in flight.
__global__ void fill_kernel(const void* edge, int E, const int* flag,
                            int* cursor, int* __restrict__ csr_src) {
    const int is64 = *flag;
    const int st   = blockDim.x;
    const int e0   = blockIdx.x * (st * 4) + threadIdx.x;
    const int e1 = e0 + st, e2 = e0 + 2 * st, e3 = e0 + 3 * st;
    const bool v0 = e0 < E, v1 = e1 < E, v2 = e2 < E, v3 = e3 < E;

    int s0 = 0, d0 = 0, s1 = 0, d1 = 0, s2 = 0, d2 = 0, s3 = 0, d3 = 0;
    if (v0) { s0 = load_idx(edge, e0, is64); d0 = load_idx(edge, E + e0, is64); }
    if (v1) { s1 = load_idx(edge, e1, is64); d1 = load_idx(edge, E + e1, is64); }
    if (v2) { s2 = load_idx(edge, e2, is64); d2 = load_idx(edge, E + e2, is64); }
    if (v3) { s3 = load_idx(edge, e3, is64); d3 = load_idx(edge, E + e3, is64); }

    int p0 = 0, p1 = 0, p2 = 0, p3 = 0;
    if (v0) p0 = atomicAdd(&cursor[d0], 1);
    if (v1) p1 = atomicAdd(&cursor[d1], 1);
    if (v2) p2 = atomicAdd(&cursor[d2], 1);
    if (v3) p3 = atomicAdd(&cursor[d3], 1);

    if (v0) csr_src[p0] = s0;
    if (v1) csr_src[p1] = s1;
    if (v2) csr_src[p2] = s2;
    if (v3) csr_src[p3] = s3;
}

// ---------------------------------------------------------------------------
// Fused SAGE layer, persistent blocks: weights staged ONCE per block, then a
// grid-stride loop over node groups with NO barriers (sAgg/sH are per-wave
// private — wave-synchronous LDS). Gather: 8 independent loads in flight;
// tail handled as one guarded parallel batch (not a serial loop).
// MODE: 0 = relu, 2 = log_softmax (final layer).
template <int DIN, int MODE>
__global__ void sage_layer_kernel(const float* __restrict__ h,
                                  const int* __restrict__ offsets,
                                  const int* __restrict__ csr_src,
                                  const float* __restrict__ Wl,
                                  const float* __restrict__ bl,
                                  const float* __restrict__ Wr,
                                  float* __restrict__ out) {
    __shared__ float sWl[DIN * CD];
    __shared__ float sWr[DIN * CD];
    __shared__ float sb[CD];
    __shared__ float sAgg[NPB][DIN];
    __shared__ float sH[NPB][DIN];

    const int tid = threadIdx.x;
    for (int i = tid; i < DIN * CD; i += blockDim.x) {
        sWl[i] = Wl[i];
        sWr[i] = Wr[i];
    }
    if (tid < CD) sb[tid] = bl[tid];
    __syncthreads();                      // the ONLY barrier in this kernel

    const int g    = tid >> 6;            // wave id = local node slot
    const int lane = tid & 63;
    const int ngrp = (NN + NPB - 1) / NPB;

    for (int grp = blockIdx.x; grp < ngrp; grp += gridDim.x) {
        const int n = grp * NPB + g;
        if (n < NN) {
            const int beg = offsets[n];
            const int end = offsets[n + 1];
            if (DIN == 32) {
                // 2 neighbors per wave (halves), unroll 4 per half = 8 in flight.
                const int p = lane >> 5;
                const int j = lane & 31;
                float a0 = -INFINITY, a1 = -INFINITY, a2 = -INFINITY, a3 = -INFINITY;
                int i = beg + p;
                for (; i + 6 < end; i += 8) {
                    int s0 = csr_src[i],     s1 = csr_src[i + 2];
                    int s2 = csr_src[i + 4], s3 = csr_src[i + 6];
                    a0 = fmaxf(a0, h[(size_t)s0 * 32 + j]);
                    a1 = fmaxf(a1, h[(size_t)s1 * 32 + j]);
                    a2 = fmaxf(a2, h[(size_t)s2 * 32 + j]);
                    a3 = fmaxf(a3, h[(size_t)s3 * 32 + j]);
                }
                // guarded parallel tail (≤3 per half)
                if (i < end)     a0 = fmaxf(a0, h[(size_t)csr_src[i] * 32 + j]);
                if (i + 2 < end) a1 = fmaxf(a1, h[(size_t)csr_src[i + 2] * 32 + j]);
                if (i + 4 < end) a2 = fmaxf(a2, h[(size_t)csr_src[i + 4] * 32 + j]);
                float a = fmaxf(fmaxf(a0, a1), fmaxf(a2, a3));
                a = fmaxf(a, __shfl_xor(a, 32));
                if (lane < 32) {
                    sAgg[g][j] = (a == -INFINITY) ? 0.0f : a;
                    sH[g][j]   = h[(size_t)n * 32 + j];
                }
            } else {
                if (lane < DIN) {
                    float a0 = -INFINITY, a1 = -INFINITY, a2 = -INFINITY, a3 = -INFINITY;
                    float a4 = -INFINITY, a5 = -INFINITY, a6 = -INFINITY, a7 = -INFINITY;
                    int i = beg;
                    for (; i + 8 <= end; i += 8) {
                        int s0 = csr_src[i],     s1 = csr_src[i + 1];
                        int s2 = csr_src[i + 2], s3 = csr_src[i + 3];
                        int s4 = csr_src[i + 4], s5 = csr_src[i + 5];
                        int s6 = csr_src[i + 6], s7 = csr_src[i + 7];
                        a0 = fmaxf(a0, h[(size_t)s0 * DIN + lane]);
                        a1 = fmaxf(a1, h[(size_t)s1 * DIN + lane]);
                        a2 = fmaxf(a2, h[(size_t)s2 * DIN + lane]);
                        a3 = fmaxf(a3, h[(size_t)s3 * DIN + lane]);
                        a4 = fmaxf(a4, h[(size_t)s4 * DIN + lane]);
                        a5 = fmaxf(a5, h[(size_t)s5 * DIN + lane]);
                        a6 = fmaxf(a6, h[(size_t)s6 * DIN + lane]);
                        a7 = fmaxf(a7, h[(size_t)s7 * DIN + lane]);
                    }
                    // guarded parallel tail (≤7), all independent
                    if (i < end)     a0 = fmaxf(a0, h[(size_t)csr_src[i] * DIN + lane]);
                    if (i + 1 < end) a1 = fmaxf(a1, h[(size_t)csr_src[i + 1] * DIN + lane]);
                    if (i + 2 < end) a2 = fmaxf(a2, h[(size_t)csr_src[i + 2] * DIN + lane]);
                    if (i + 3 < end) a3 = fmaxf(a3, h[(size_t)csr_src[i + 3] * DIN + lane]);
                    if (i + 4 < end) a4 = fmaxf(a4, h[(size_t)csr_src[i + 4] * DIN + lane]);
                    if (i + 5 < end) a5 = fmaxf(a5, h[(size_t)csr_src[i + 5] * DIN + lane]);
                    if (i + 6 < end) a6 = fmaxf(a6, h[(size_t)csr_src[i + 6] * DIN + lane]);
                    float a = fmaxf(fmaxf(fmaxf(a0, a1), fmaxf(a2, a3)),
                                    fmaxf(fmaxf(a4, a5), fmaxf(a6, a7)));
                    sAgg[g][lane] = (a == -INFINITY) ? 0.0f : a;
                    sH[g][lane]   = h[(size_t)n * DIN + lane];
                }
            }
        }
        // no __syncthreads: same-wave LDS write->read, HW+compiler ordered

        if (n < NN) {
            const int p  = lane >> 5;
            const int j  = lane & 31;
            const int KH = DIN / 2;                  // 25 or 16
            const int k0 = p * KH;
            const int k1 = (p == 1) ? DIN : KH;
            float part = (p == 0) ? sb[j] : 0.0f;
#pragma unroll
            for (int k = k0; k < k1; ++k) {
                part += sAgg[g][k] * sWl[k * CD + j] + sH[g][k] * sWr[k * CD + j];
            }
            float acc = part + __shfl_xor(part, 32);
            if (lane < 32) {
                if (MODE == 0) acc = fmaxf(acc, 0.0f);
                if (MODE == 2) {
                    float m = acc;
                    for (int off = 16; off > 0; off >>= 1) m = fmaxf(m, __shfl_xor(m, off, 32));
                    float ex = expf(acc - m);
                    float s = ex;
                    for (int off = 16; off > 0; off >>= 1) s += __shfl_xor(s, off, 32);
                    acc = acc - m - logf(s);
                }
                out[(size_t)n * CD + j] = acc;
            }
        }
    }
}

// ---------------------------------------------------------------------------
extern "C" void kernel_launch(void* const* d_in, const int* in_sizes, int n_in,
                              void* d_out, int out_size, void* d_ws, size_t ws_size,
                              hipStream_t stream) {
    const float* x    = (const float*)d_in[0];
    const void*  edge = d_in[1];
    const float* Wl1 = (const float*)d_in[2];
    const float* bl1 = (const float*)d_in[3];
    const float* Wr1 = (const float*)d_in[4];
    const float* Wl2 = (const float*)d_in[5];
    const float* bl2 = (const float*)d_in[6];
    const float* Wr2 = (const float*)d_in[7];
    const float* Wl3 = (const float*)d_in[8];
    const float* bl3 = (const float*)d_in[9];
    const float* Wr3 = (const float*)d_in[10];

    const int E = in_sizes[1] / 2;

    // Workspace carve-up (256B aligned). Total ≈ 32.8 MB.
    char* ws = (char*)d_ws;
    size_t off = 0;
    auto carve = [&](size_t bytes) {
        void* p = ws + off;
        off = (off + bytes + 255) & ~(size_t)255;
        return p;
    };
    int*   counts    = (int*)  carve((size_t)NN * 4);       // aliased as cursor
    int*   cursor    = counts;
    int*   offsets   = (int*)  carve((size_t)(NN + 1) * 4);
    int*   flag      = (int*)  carve(4);
    int*   blockSums = (int*)  carve((size_t)SCAN_NB * 4);
    int*   csr_src   = (int*)  carve((size_t)E * 4);
    float* h1        = (float*)carve((size_t)NN * CD * 4);
    float* h2        = (float*)carve((size_t)NN * CD * 4);
    float* out       = (float*)d_out;
    (void)ws_size; (void)n_in; (void)out_size;

    hipMemsetAsync(counts, 0, (size_t)NN * 4, stream);
    detect_idx64<<<1, 64, 0, stream>>>(edge, flag);

    const int eb1 = (E + 255) / 256;
    const int eb4 = (E + 1023) / 1024;
    hist_kernel<<<eb1, 256, 0, stream>>>(edge, E, flag, counts);
    scan_partial_kernel<<<SCAN_NB, 256, 0, stream>>>(counts, blockSums);
    scan_bases_kernel<<<1, 256, 0, stream>>>(blockSums);
    scan_final_kernel<<<SCAN_NB, 256, 0, stream>>>(counts, blockSums, offsets, cursor);
    fill_kernel<<<eb4, 256, 0, stream>>>(edge, E, flag, cursor, csr_src);

    sage_layer_kernel<50, 0><<<LGRID, 256, 0, stream>>>(x,  offsets, csr_src, Wl1, bl1, Wr1, h1);
    sage_layer_kernel<32, 0><<<LGRID, 256, 0, stream>>>(h1, offsets, csr_src, Wl2, bl2, Wr2, h2);
    sage_layer_kernel<32, 2><<<LGRID, 256, 0, stream>>>(h2, offsets, csr_src, Wl3, bl3, Wr3, out);
}